// Round 6
// baseline (49.572 us; speedup 1.0000x reference)
//
#include <hip/hip_runtime.h>

// Integrate-and-fire scan: x (T*B, C, H, W) f32, T=8, viewed as (T, N).
// R5 lesson: system-scope store-bypass (sc0 sc1) breaks coherence with the
// harness's readback -> reverted. This round tests the latency hypothesis:
// 2 vec4 columns per thread (split halves, both coalesced), 16 independent
// loads in flight per wave instead of 8.
//
// Traffic per replay (R4 counters): FETCH 64 MiB (half input L3-resident),
// WRITE 128 MiB -> 4.3 TB/s at 46.7 us vs ~6.3 TB/s copy ceiling.

#define T_STEPS 8

typedef float f32x4 __attribute__((ext_vector_type(4)));

__global__ __launch_bounds__(256) void if_scan_kernel(
    const f32x4* __restrict__ x,
    const float* __restrict__ thr_p,
    f32x4* __restrict__ out,
    int n4)   // N/4 vec4 elements per timestep
{
    const int n4h = n4 >> 1;
    const int i   = blockIdx.x * blockDim.x + threadIdx.x;
    if (i >= n4h) return;
    const int i2  = i + n4h;
    const float th = thr_p[0];

    // 16 independent loads issued up front for max memory-level parallelism.
    f32x4 xa[T_STEPS], xb[T_STEPS];
    #pragma unroll
    for (int t = 0; t < T_STEPS; ++t) {
        xa[t] = x[(size_t)t * n4 + i];
        xb[t] = x[(size_t)t * n4 + i2];
    }

    f32x4 ma = {0.f, 0.f, 0.f, 0.f};
    f32x4 mb = {0.f, 0.f, 0.f, 0.f};
    #pragma unroll
    for (int t = 0; t < T_STEPS; ++t) {
        f32x4 sa, sb;
        ma += xa[t];
        mb += xb[t];
        #pragma unroll
        for (int j = 0; j < 4; ++j) {
            sa[j] = (ma[j] - th > 0.f) ? 1.f : 0.f;
            ma[j] = (sa[j] != 0.f) ? 0.f : ma[j];
            sb[j] = (mb[j] - th > 0.f) ? 1.f : 0.f;
            mb[j] = (sb[j] != 0.f) ? 0.f : mb[j];
        }
        __builtin_nontemporal_store(sa, &out[(size_t)t * n4 + i]);
        __builtin_nontemporal_store(sb, &out[(size_t)t * n4 + i2]);
    }
}

extern "C" void kernel_launch(void* const* d_in, const int* in_sizes, int n_in,
                              void* d_out, int out_size, void* d_ws, size_t ws_size,
                              hipStream_t stream) {
    const float* x   = (const float*)d_in[0];
    const float* thr = (const float*)d_in[1];
    float* out       = (float*)d_out;

    const int total = in_sizes[0];       // T*B*C*H*W = 33,554,432
    const int N     = total / T_STEPS;   // per-timestep elements = 4,194,304
    const int n4    = N / 4;             // vec4 count = 1,048,576

    const int threads = 256;
    const int blocks  = ((n4 / 2) + threads - 1) / threads;  // 2048

    if_scan_kernel<<<blocks, threads, 0, stream>>>(
        (const f32x4*)x, thr, (f32x4*)out, n4);
}